// Round 5
// baseline (43.519 us; speedup 1.0000x reference)
//
#include <hip/hip_runtime.h>

#define E  9
#define B_ 8
#define H_ 224
#define W_ 224
#define C_ 32
#define TH 8                        // output rows marched per thread
#define WT 32                       // w pixels per block
#define STRIPS (H_ / TH)            // 28
#define WTILES (W_ / WT)            // 7
#define NBLK (B_ * STRIPS * WTILES) // 1568 (divisible by 8 -> clean XCD swizzle)

__global__ __launch_bounds__(64) void fm_prep(const float* __restrict__ mask,
                                              float* __restrict__ m_out) {
    int t = threadIdx.x;           // single wave of 64
    float v[5];
    float mx = 0.0f;
#pragma unroll
    for (int i = 0; i < 5; ++i) {
        int idx = t + i * 64;
        v[i] = (idx < E * C_) ? fabsf(mask[idx]) : 0.0f;
        mx = fmaxf(mx, v[i]);
    }
#pragma unroll
    for (int off = 32; off >= 1; off >>= 1)
        mx = fmaxf(mx, __shfl_xor(mx, off));
    float inv = 1.0f / (mx + 1e-6f);
#pragma unroll
    for (int i = 0; i < 5; ++i) {
        int idx = t + i * 64;
        if (idx < E * C_) m_out[idx] = v[i] * inv;
    }
}

__global__ __launch_bounds__(256) void fm_main(const float* __restrict__ inp,
                                               const float* __restrict__ kern,
                                               const float* __restrict__ m,
                                               float* __restrict__ out) {
    // Bijective XCD-chunk swizzle: each XCD gets one batch image (196 blocks).
    int bid = blockIdx.x;
    int swz = (bid & 7) * (NBLK / 8) + (bid >> 3);
    int bw  = swz % WTILES;
    int t2  = swz / WTILES;
    int hs  = (t2 % STRIPS) * TH;   // strip start row
    int b   = t2 / STRIPS;

    int t  = threadIdx.x;
    int cq = (t & 7) << 2;          // channel quad: 0,4,...,28
    int wl = t >> 3;                // 0..31
    int w  = bw * WT + wl;

    // Loop-invariant coefficients -> registers (72 VGPRs). 1152 B total,
    // L2-resident broadcast; loaded once, reused for all TH rows.
    // (R1-R3 re-read these from LDS 18x b128 per row: the LDS return path
    //  (~12 cyc/b128, per-CU shared) was ~1.6x oversubscribed vs VALU.)
    float4 cm[E], ck[E];
#pragma unroll
    for (int e = 0; e < E; ++e) {
        cm[e] = *reinterpret_cast<const float4*>(m    + e * C_ + cq);
        ck[e] = *reinterpret_cast<const float4*>(kern + e * C_ + cq);
    }

    const float* base = inp + (((size_t)b * H_ * W_ + w) * C_) + cq;
    bool wm = (w > 0);
    bool wp = (w < W_ - 1);

    const float4 z4 = make_float4(0.f, 0.f, 0.f, 0.f);

    float4 win[3][3];   // [ring slot][x-offset -1,0,+1]

    auto ld3 = [&](int hh, float4* r) {
        if ((unsigned)hh < (unsigned)H_) {   // block-uniform branch
            const float* p = base + (size_t)hh * (W_ * C_);
            r[0] = wm ? *reinterpret_cast<const float4*>(p - C_) : z4;
            r[1] = *reinterpret_cast<const float4*>(p);
            r[2] = wp ? *reinterpret_cast<const float4*>(p + C_) : z4;
        } else {
            r[0] = z4; r[1] = z4; r[2] = z4;
        }
    };

    ld3(hs - 1, win[0]);
    ld3(hs,     win[1]);

    const float inv9 = 1.0f / 9.0f;

#pragma unroll
    for (int s = 0; s < TH; ++s) {
        ld3(hs + s + 1, win[(s + 2) % 3]);

        const float4* rm1 = win[(s + 0) % 3];   // row h-1
        const float4* r0  = win[(s + 1) % 3];   // row h
        const float4* rp1 = win[(s + 2) % 3];   // row h+1

        // tap order: e=0 center, then (y,x) raster skipping center
        float4 taps[E];
        taps[0] = r0[1];
        taps[1] = rm1[0]; taps[2] = rm1[1]; taps[3] = rm1[2];
        taps[4] = r0[0];  taps[5] = r0[2];
        taps[6] = rp1[0]; taps[7] = rp1[1]; taps[8] = rp1[2];

        float4 a[E];
        float n0 = 0.f, n1 = 0.f, n2 = 0.f, n3 = 0.f;
        float s0 = 0.f, s1 = 0.f, s2 = 0.f, s3 = 0.f;

#pragma unroll
        for (int e = 0; e < E; ++e) {
            float dx = fmaf(taps[e].x, cm[e].x, -ck[e].x);
            float dy = fmaf(taps[e].y, cm[e].y, -ck[e].y);
            float dz = fmaf(taps[e].z, cm[e].z, -ck[e].z);
            float dw = fmaf(taps[e].w, cm[e].w, -ck[e].w);
            a[e].x = fabsf(dx); a[e].y = fabsf(dy);
            a[e].z = fabsf(dz); a[e].w = fabsf(dw);
            n0 += a[e].x; n1 += a[e].y; n2 += a[e].z; n3 += a[e].w;
            s0 += dx; s1 += dy; s2 += dz; s3 += dw;
        }

        float m0 = s0 * inv9, m1 = s1 * inv9, m2 = s2 * inv9, m3 = s3 * inv9;

        float v0 = 0.f, v1 = 0.f, v2 = 0.f, v3 = 0.f;
#pragma unroll
        for (int e = 0; e < E; ++e) {
            v0 += fabsf(a[e].x - m0);
            v1 += fabsf(a[e].y - m1);
            v2 += fabsf(a[e].z - m2);
            v3 += fabsf(a[e].w - m3);
        }

        float4 o;
        o.x = (1.0f - v0 * inv9) * (1.0f - n0 * inv9);
        o.y = (1.0f - v1 * inv9) * (1.0f - n1 * inv9);
        o.z = (1.0f - v2 * inv9) * (1.0f - n2 * inv9);
        o.w = (1.0f - v3 * inv9) * (1.0f - n3 * inv9);

        float* op = out + (((size_t)b * H_ + (hs + s)) * W_ + w) * C_ + cq;
        *reinterpret_cast<float4*>(op) = o;
    }
}

extern "C" void kernel_launch(void* const* d_in, const int* in_sizes, int n_in,
                              void* d_out, int out_size, void* d_ws, size_t ws_size,
                              hipStream_t stream) {
    const float* inp  = (const float*)d_in[0];
    const float* kern = (const float*)d_in[1];
    const float* mask = (const float*)d_in[2];
    float* out = (float*)d_out;
    float* m   = (float*)d_ws;   // E*C_ floats = 1152 B

    fm_prep<<<1, 64, 0, stream>>>(mask, m);
    fm_main<<<NBLK, 256, 0, stream>>>(inp, kern, m, out);
}

// Round 6
// 38.083 us; speedup vs baseline: 1.1428x; 1.1428x over previous
//
#include <hip/hip_runtime.h>

#define E  9
#define B_ 8
#define H_ 224
#define W_ 224
#define C_ 32
#define TH 7                        // 224/7=32 strips -> 1792 blocks = exactly 7/CU
#define WT 32                       // w pixels per block
#define STRIPS (H_ / TH)            // 32
#define WTILES (W_ / WT)            // 7
#define NBLK (B_ * STRIPS * WTILES) // 1792 (=224/XCD: one batch image per XCD)

typedef float    v2f __attribute__((ext_vector_type(2)));
typedef unsigned uv2 __attribute__((ext_vector_type(2)));

__device__ __forceinline__ v2f vabs2(v2f x) {
    uv2 u = __builtin_bit_cast(uv2, x);
    u &= 0x7fffffffu;
    return __builtin_bit_cast(v2f, u);
}

__global__ __launch_bounds__(64) void fm_prep(const float* __restrict__ mask,
                                              float* __restrict__ m_out) {
    int t = threadIdx.x;           // single wave of 64
    float v[5];
    float mx = 0.0f;
#pragma unroll
    for (int i = 0; i < 5; ++i) {
        int idx = t + i * 64;
        v[i] = (idx < E * C_) ? fabsf(mask[idx]) : 0.0f;
        mx = fmaxf(mx, v[i]);
    }
#pragma unroll
    for (int off = 32; off >= 1; off >>= 1)
        mx = fmaxf(mx, __shfl_xor(mx, off));
    float inv = 1.0f / (mx + 1e-6f);
#pragma unroll
    for (int i = 0; i < 5; ++i) {
        int idx = t + i * 64;
        if (idx < E * C_) m_out[idx] = v[i] * inv;
    }
}

__global__ __launch_bounds__(256) void fm_main(const float* __restrict__ inp,
                                               const float* __restrict__ kern,
                                               const float* __restrict__ m,
                                               float* __restrict__ out) {
    __shared__ float s_m[E * C_];
    __shared__ float s_nk[E * C_];   // NEGATED kernel -> diff is one packed fma
    for (int i = threadIdx.x; i < E * C_; i += 256) {
        s_m[i]  = m[i];
        s_nk[i] = -kern[i];
    }
    __syncthreads();

    // Bijective XCD-chunk swizzle: each XCD gets one batch image (224 blocks).
    int bid = blockIdx.x;
    int swz = (bid & 7) * (NBLK / 8) + (bid >> 3);
    int bw  = swz % WTILES;
    int t2  = swz / WTILES;
    int hs  = (t2 % STRIPS) * TH;   // strip start row
    int b   = t2 / STRIPS;

    int t  = threadIdx.x;
    int cq = (t & 7) << 2;          // channel quad: 0,4,...,28
    int wl = t >> 3;                // 0..31
    int w  = bw * WT + wl;

    const float* base = inp + (((size_t)b * H_ * W_ + w) * C_) + cq;
    bool wm = (w > 0);
    bool wp = (w < W_ - 1);

    const float4 z4 = make_float4(0.f, 0.f, 0.f, 0.f);

    float4 win[3][3];   // [ring slot][x-offset -1,0,+1]

    auto ld3 = [&](int hh, float4* r) {
        if ((unsigned)hh < (unsigned)H_) {   // block-uniform branch
            const float* p = base + (size_t)hh * (W_ * C_);
            r[0] = wm ? *reinterpret_cast<const float4*>(p - C_) : z4;
            r[1] = *reinterpret_cast<const float4*>(p);
            r[2] = wp ? *reinterpret_cast<const float4*>(p + C_) : z4;
        } else {
            r[0] = z4; r[1] = z4; r[2] = z4;
        }
    };

    ld3(hs - 1, win[0]);
    ld3(hs,     win[1]);

    const float inv9 = 1.0f / 9.0f;
    const v2f inv9v = {inv9, inv9};
    const v2f onev  = {1.0f, 1.0f};

#pragma unroll
    for (int s = 0; s < TH; ++s) {
        ld3(hs + s + 1, win[(s + 2) % 3]);

        const float4* rm1 = win[(s + 0) % 3];   // row h-1
        const float4* r0  = win[(s + 1) % 3];   // row h
        const float4* rp1 = win[(s + 2) % 3];   // row h+1

        // tap order: e=0 center, then (y,x) raster skipping center
        float4 taps[E];
        taps[0] = r0[1];
        taps[1] = rm1[0]; taps[2] = rm1[1]; taps[3] = rm1[2];
        taps[4] = r0[0];  taps[5] = r0[2];
        taps[6] = rp1[0]; taps[7] = rp1[1]; taps[8] = rp1[2];

        v2f alo[E], ahi[E];
        v2f nlo = {0.f, 0.f}, nhi = {0.f, 0.f};
        v2f slo = {0.f, 0.f}, shi = {0.f, 0.f};

#pragma unroll
        for (int e = 0; e < E; ++e) {
            const v2f* tp = reinterpret_cast<const v2f*>(&taps[e]);
            const v2f* mp = reinterpret_cast<const v2f*>(s_m  + e * C_ + cq);
            const v2f* kp = reinterpret_cast<const v2f*>(s_nk + e * C_ + cq);
            v2f dlo = tp[0] * mp[0] + kp[0];    // v_pk_fma_f32
            v2f dhi = tp[1] * mp[1] + kp[1];
            v2f al = vabs2(dlo), ah = vabs2(dhi);
            alo[e] = al; ahi[e] = ah;
            nlo += al; nhi += ah;               // v_pk_add_f32
            slo += dlo; shi += dhi;
        }

        v2f mlo = slo * inv9v, mhi = shi * inv9v;

        v2f vlo = {0.f, 0.f}, vhi = {0.f, 0.f};
#pragma unroll
        for (int e = 0; e < E; ++e) {
            vlo += vabs2(alo[e] - mlo);
            vhi += vabs2(ahi[e] - mhi);
        }

        v2f olo = (onev - vlo * inv9v) * (onev - nlo * inv9v);
        v2f ohi = (onev - vhi * inv9v) * (onev - nhi * inv9v);

        float4 o;
        o.x = olo.x; o.y = olo.y; o.z = ohi.x; o.w = ohi.y;

        float* op = out + (((size_t)b * H_ + (hs + s)) * W_ + w) * C_ + cq;
        *reinterpret_cast<float4*>(op) = o;
    }
}

extern "C" void kernel_launch(void* const* d_in, const int* in_sizes, int n_in,
                              void* d_out, int out_size, void* d_ws, size_t ws_size,
                              hipStream_t stream) {
    const float* inp  = (const float*)d_in[0];
    const float* kern = (const float*)d_in[1];
    const float* mask = (const float*)d_in[2];
    float* out = (float*)d_out;
    float* m   = (float*)d_ws;   // E*C_ floats = 1152 B

    fm_prep<<<1, 64, 0, stream>>>(mask, m);
    fm_main<<<NBLK, 256, 0, stream>>>(inp, kern, m, out);
}

// Round 8
// 32.329 us; speedup vs baseline: 1.3461x; 1.1780x over previous
//
#include <hip/hip_runtime.h>

#define E  9
#define B_ 8
#define H_ 224
#define W_ 224
#define C_ 32
#define TH 7                        // 224/7=32 strips -> 1792 blocks = exactly 7/CU
#define WT 32                       // w pixels per block
#define STRIPS (H_ / TH)            // 32
#define WTILES (W_ / WT)            // 7
#define NBLK (B_ * STRIPS * WTILES) // 1792 (one batch image per XCD after swizzle)

typedef float    v2f __attribute__((ext_vector_type(2)));
typedef float    v4f __attribute__((ext_vector_type(4)));   // clang-native: ok for nontemporal builtin
typedef unsigned uv2 __attribute__((ext_vector_type(2)));

__device__ __forceinline__ v2f vabs2(v2f x) {
    uv2 u = __builtin_bit_cast(uv2, x);
    u &= 0x7fffffffu;
    return __builtin_bit_cast(v2f, u);
}

__global__ __launch_bounds__(256) void fm_main(const float* __restrict__ inp,
                                               const float* __restrict__ kern,
                                               const float* __restrict__ mask,
                                               float* __restrict__ out) {
    __shared__ float s_m[E * C_];
    __shared__ float s_nk[E * C_];   // NEGATED kernel -> diff is one packed fma
    __shared__ float s_red[4];

    // ---- Folded prep: every block computes global max(|mask|) over 288 elems.
    int t = threadIdx.x;
    {
        float a0 = (t < E * C_) ? fabsf(mask[t]) : 0.0f;
        float a1 = (t < E * C_ - 256) ? fabsf(mask[t + 256]) : 0.0f;
        float mx = fmaxf(a0, a1);
#pragma unroll
        for (int off = 32; off >= 1; off >>= 1)
            mx = fmaxf(mx, __shfl_xor(mx, off));
        if ((t & 63) == 0) s_red[t >> 6] = mx;
        __syncthreads();
        float gmx = fmaxf(fmaxf(s_red[0], s_red[1]), fmaxf(s_red[2], s_red[3]));
        float inv = 1.0f / (gmx + 1e-6f);
        if (t < E * C_) {
            s_m[t]  = fabsf(mask[t]) * inv;
            s_nk[t] = -kern[t];
            if (t < E * C_ - 256) {
                s_m[t + 256]  = fabsf(mask[t + 256]) * inv;
                s_nk[t + 256] = -kern[t + 256];
            }
        }
        __syncthreads();
    }

    // Bijective XCD-chunk swizzle: each XCD gets one batch image (224 blocks).
    int bid = blockIdx.x;
    int swz = (bid & 7) * (NBLK / 8) + (bid >> 3);
    int bw  = swz % WTILES;
    int t2  = swz / WTILES;
    int hs  = (t2 % STRIPS) * TH;   // strip start row
    int b   = t2 / STRIPS;

    int cq = (t & 7) << 2;          // channel quad: 0,4,...,28
    int wl = t >> 3;                // 0..31
    int w  = bw * WT + wl;

    const float* base = inp + (((size_t)b * H_ * W_ + w) * C_) + cq;
    bool wm = (w > 0);
    bool wp = (w < W_ - 1);

    const float4 z4 = make_float4(0.f, 0.f, 0.f, 0.f);

    float4 win[3][3];   // [ring slot][x-offset -1,0,+1]

    auto ld3 = [&](int hh, float4* r) {
        if ((unsigned)hh < (unsigned)H_) {   // block-uniform branch
            const float* p = base + (size_t)hh * (W_ * C_);
            r[0] = wm ? *reinterpret_cast<const float4*>(p - C_) : z4;
            r[1] = *reinterpret_cast<const float4*>(p);
            r[2] = wp ? *reinterpret_cast<const float4*>(p + C_) : z4;
        } else {
            r[0] = z4; r[1] = z4; r[2] = z4;
        }
    };

    ld3(hs - 1, win[0]);
    ld3(hs,     win[1]);

    const float inv9 = 1.0f / 9.0f;
    const v2f inv9v = {inv9, inv9};
    const v2f onev  = {1.0f, 1.0f};

#pragma unroll
    for (int s = 0; s < TH; ++s) {
        ld3(hs + s + 1, win[(s + 2) % 3]);

        const float4* rm1 = win[(s + 0) % 3];   // row h-1
        const float4* r0  = win[(s + 1) % 3];   // row h
        const float4* rp1 = win[(s + 2) % 3];   // row h+1

        // tap order: e=0 center, then (y,x) raster skipping center
        float4 taps[E];
        taps[0] = r0[1];
        taps[1] = rm1[0]; taps[2] = rm1[1]; taps[3] = rm1[2];
        taps[4] = r0[0];  taps[5] = r0[2];
        taps[6] = rp1[0]; taps[7] = rp1[1]; taps[8] = rp1[2];

        v2f alo[E], ahi[E];
        v2f nlo = {0.f, 0.f}, nhi = {0.f, 0.f};
        v2f slo = {0.f, 0.f}, shi = {0.f, 0.f};

#pragma unroll
        for (int e = 0; e < E; ++e) {
            const v2f* tp = reinterpret_cast<const v2f*>(&taps[e]);
            const v2f* mp = reinterpret_cast<const v2f*>(s_m  + e * C_ + cq);
            const v2f* kp = reinterpret_cast<const v2f*>(s_nk + e * C_ + cq);
            v2f dlo = tp[0] * mp[0] + kp[0];    // v_pk_fma_f32
            v2f dhi = tp[1] * mp[1] + kp[1];
            v2f al = vabs2(dlo), ah = vabs2(dhi);
            alo[e] = al; ahi[e] = ah;
            nlo += al; nhi += ah;               // v_pk_add_f32
            slo += dlo; shi += dhi;
        }

        v2f mlo = slo * inv9v, mhi = shi * inv9v;

        v2f vlo = {0.f, 0.f}, vhi = {0.f, 0.f};
#pragma unroll
        for (int e = 0; e < E; ++e) {
            vlo += vabs2(alo[e] - mlo);
            vhi += vabs2(ahi[e] - mhi);
        }

        v2f olo = (onev - vlo * inv9v) * (onev - nlo * inv9v);
        v2f ohi = (onev - vhi * inv9v) * (onev - nhi * inv9v);

        v4f o;
        o.x = olo.x; o.y = olo.y; o.z = ohi.x; o.w = ohi.y;

        // Output is write-once/never-read: non-temporal keeps it out of L2/L3
        // so the input working set survives across rows/replays.
        float* op = out + (((size_t)b * H_ + (hs + s)) * W_ + w) * C_ + cq;
        __builtin_nontemporal_store(o, reinterpret_cast<v4f*>(op));
    }
}

extern "C" void kernel_launch(void* const* d_in, const int* in_sizes, int n_in,
                              void* d_out, int out_size, void* d_ws, size_t ws_size,
                              hipStream_t stream) {
    const float* inp  = (const float*)d_in[0];
    const float* kern = (const float*)d_in[1];
    const float* mask = (const float*)d_in[2];
    float* out = (float*)d_out;

    fm_main<<<NBLK, 256, 0, stream>>>(inp, kern, mask, out);
}